// Round 10
// baseline (327.633 us; speedup 1.0000x reference)
//
#include <hip/hip_runtime.h>
#include <hip/hip_bf16.h>
#include <hip/hip_fp16.h>
#include <cstdint>

#define NN 20000
#define EE 320000
#define ETOT (EE + NN)

using f32x4 = __attribute__((ext_vector_type(4))) float;
using f16x8 = __attribute__((ext_vector_type(8))) _Float16;
typedef unsigned short ushortT;

// ---------------- fused preprocessing: x-cast + weight transposes + degree hist ----------------
__global__ __launch_bounds__(256) void preproc_kernel(
    const float* __restrict__ x, __half* __restrict__ x16,
    const float* __restrict__ w1, ushortT* __restrict__ w1t,
    const float* __restrict__ w2, ushortT* __restrict__ w2t,
    const float* __restrict__ w3, ushortT* __restrict__ w3t,
    const int* __restrict__ ei, int* __restrict__ deg)
{
  constexpr int N0 = NN * 512;        // x cast
  constexpr int N1 = 512 * 1024;      // w1 transpose
  constexpr int N2 = 1024 * 256;      // w2 transpose
  constexpr int N3 = 256 * 64;        // w3 transpose
  constexpr int TOT = N0 + N1 + N2 + N3 + ETOT;
  for (int i = blockIdx.x * 256 + threadIdx.x; i < TOT; i += gridDim.x * 256) {
    int j = i;
    if (j < N0) { x16[j] = __float2half(x[j]); continue; }
    j -= N0;
    if (j < N1) {
      int k = j >> 10, c = j & 1023;
      w1t[(size_t)c * 512 + k] = __half_as_ushort(__float2half(w1[j]));
      continue;
    }
    j -= N1;
    if (j < N2) {
      int k = j >> 8, c = j & 255;
      w2t[(size_t)c * 1024 + k] = __half_as_ushort(__float2half(w2[j]));
      continue;
    }
    j -= N2;
    if (j < N3) {
      int k = j >> 6, c = j & 63;
      w3t[(size_t)c * 256 + k] = __half_as_ushort(__float2half(w3[j]));
      continue;
    }
    j -= N3;
    int d = (j < EE) ? ei[EE + j] : (j - EE);
    atomicAdd(&deg[d], 1);
  }
}

__global__ __launch_bounds__(1024) void scan_kernel(const int* __restrict__ deg,
                                                    int* __restrict__ row_ptr,
                                                    int* __restrict__ cursor) {
  __shared__ int partial[1024];
  const int t = threadIdx.x;
  constexpr int PER = (NN + 1023) / 1024;  // 20
  const int base = t * PER;
  int vals[PER];
  int local = 0;
  #pragma unroll
  for (int j = 0; j < PER; ++j) {
    int i = base + j;
    int v = (i < NN) ? deg[i] : 0;
    vals[j] = v; local += v;
  }
  partial[t] = local;
  __syncthreads();
  for (int off = 1; off < 1024; off <<= 1) {
    int x = (t >= off) ? partial[t - off] : 0;
    __syncthreads();
    partial[t] += x;
    __syncthreads();
  }
  int prefix = partial[t] - local;  // exclusive
  #pragma unroll
  for (int j = 0; j < PER; ++j) {
    int i = base + j;
    if (i < NN) { row_ptr[i] = prefix; cursor[i] = prefix; }
    prefix += vals[j];
  }
  if (t == 1023) row_ptr[NN] = prefix;
}

__global__ void scatter_kernel(const int* __restrict__ ei, int* __restrict__ cursor,
                               int* __restrict__ csr_src) {
  int i = blockIdx.x * 256 + threadIdx.x;
  if (i >= ETOT) return;
  int s, d;
  if (i < EE) { s = ei[i]; d = ei[EE + i]; } else { s = d = i - EE; }
  int pos = atomicAdd(&cursor[d], 1);
  csr_src[pos] = s;
}

// ---------------- fp16 MFMA GEMM (double-buffered, counted vmcnt) ----------------
__device__ __forceinline__ void gload16(const void* g, void* l) {
  __builtin_amdgcn_global_load_lds((const __attribute__((address_space(1))) void*)g,
                                   (__attribute__((address_space(3))) void*)l, 16, 0, 0);
}

template<int N> __device__ __forceinline__ void wait_vm() {
  if constexpr (N == 0) asm volatile("s_waitcnt vmcnt(0)" ::: "memory");
  else if constexpr (N == 2) asm volatile("s_waitcnt vmcnt(2)" ::: "memory");
  else if constexpr (N == 3) asm volatile("s_waitcnt vmcnt(3)" ::: "memory");
  else if constexpr (N == 4) asm volatile("s_waitcnt vmcnt(4)" ::: "memory");
  else if constexpr (N == 6) asm volatile("s_waitcnt vmcnt(6)" ::: "memory");
  else if constexpr (N == 8) asm volatile("s_waitcnt vmcnt(8)" ::: "memory");
  else static_assert(N <= 8, "unsupported vmcnt");
}

// C[M][Ncols] = A[M][K] * Bt[Ncols][K]^T; also es/ed = rowwise dot(h, asrc/adst) per head.
template<int BM, int BN, int FM, int FN, int CHEAD>
__global__ __launch_bounds__(256) void gemm_f16(
    const __half* __restrict__ A,
    const ushortT* __restrict__ Bt,
    __half* __restrict__ C, int M, int Ncols, int K,
    const float* __restrict__ asrc, const float* __restrict__ adst,
    float* __restrict__ es_g, float* __restrict__ ed_g, int H)
{
  constexpr int BK   = 32;
  constexpr int HALF = (BM + BN) * BK;              // elems per buffer
  constexpr int NL   = (BM * 4 + BN * 4) / 256;     // stage loads per thread
  __shared__ ushortT lds[2 * HALF];

  const int tid  = threadIdx.x;
  const int lane = tid & 63;
  const int wid  = tid >> 6;
  const int wm   = (wid >> 1) * (FM * 16);
  const int wn   = (wid & 1) * (FN * 16);
  const int row0 = blockIdx.x * BM;
  const int col0 = blockIdx.y * BN;
  const int r    = lane & 15;
  const int kg   = lane >> 4;

  const ushortT* Au = (const ushortT*)A;

  auto STAGE = [&](int buf, int k0) {
    ushortT* sA = lds + buf * HALF;
    ushortT* sB = sA + BM * BK;
    #pragma unroll
    for (int i = tid; i < BM * 4; i += 256) {
      int row = i >> 2, slot = i & 3;
      int gs = slot ^ (row & 3);
      int grow = row0 + row; if (grow > M - 1) grow = M - 1;
      gload16(Au + (size_t)grow * K + k0 + gs * 8, sA + row * BK + slot * 8);
    }
    #pragma unroll
    for (int i = tid; i < BN * 4; i += 256) {
      int row = i >> 2, slot = i & 3;
      int gs = slot ^ (row & 3);
      gload16(Bt + (size_t)(col0 + row) * K + k0 + gs * 8, sB + row * BK + slot * 8);
    }
  };

  f32x4 acc[FM][FN] = {};
  const int nt = K / BK;

  STAGE(0, 0);
  for (int t = 0; t < nt; ++t) {
    if (t + 1 < nt) { STAGE((t + 1) & 1, (t + 1) * BK); wait_vm<NL>(); }
    else            { wait_vm<0>(); }
    __builtin_amdgcn_s_barrier();
    __builtin_amdgcn_sched_barrier(0);

    const ushortT* sA = lds + (t & 1) * HALF;
    const ushortT* sB = sA + BM * BK;
    const int ks = (kg ^ (r & 3)) * 8;
    f16x8 a[FM], b[FN];
    #pragma unroll
    for (int mi = 0; mi < FM; ++mi)
      a[mi] = *(const f16x8*)(sA + (wm + mi * 16 + r) * BK + ks);
    #pragma unroll
    for (int ni = 0; ni < FN; ++ni)
      b[ni] = *(const f16x8*)(sB + (wn + ni * 16 + r) * BK + ks);
    #pragma unroll
    for (int mi = 0; mi < FM; ++mi)
      #pragma unroll
      for (int ni = 0; ni < FN; ++ni)
        acc[mi][ni] = __builtin_amdgcn_mfma_f32_16x16x32_f16(a[mi], b[ni], acc[mi][ni], 0, 0, 0);
    __builtin_amdgcn_sched_barrier(0);
    __builtin_amdgcn_s_barrier();
  }

  // C-write
  #pragma unroll
  for (int mi = 0; mi < FM; ++mi) {
    int rb = row0 + wm + mi * 16 + (lane >> 4) * 4;
    #pragma unroll
    for (int ni = 0; ni < FN; ++ni) {
      int cc = col0 + wn + ni * 16 + (lane & 15);
      #pragma unroll
      for (int j = 0; j < 4; ++j) {
        int rr = rb + j;
        if (rr < M) C[(size_t)rr * Ncols + cc] = __float2half(acc[mi][ni][j]);
      }
    }
  }

  // fused es/ed epilogue. Wave col-group covers FN*16 cols; head spans CHEAD cols.
  constexpr bool DIRECT = (CHEAD == FN * 16);
  float av[FN], dv[FN];
  #pragma unroll
  for (int ni = 0; ni < FN; ++ni) {
    int cc = col0 + wn + ni * 16 + (lane & 15);
    av[ni] = asrc[cc];
    dv[ni] = adst[cc];
  }
  float ps[FM][4], pd[FM][4];
  #pragma unroll
  for (int mi = 0; mi < FM; ++mi)
    #pragma unroll
    for (int j = 0; j < 4; ++j) {
      float s = 0.f, d = 0.f;
      #pragma unroll
      for (int ni = 0; ni < FN; ++ni) {
        float v = acc[mi][ni][j];
        s += v * av[ni];
        d += v * dv[ni];
      }
      #pragma unroll
      for (int off = 8; off; off >>= 1) {
        s += __shfl_xor(s, off);
        d += __shfl_xor(d, off);
      }
      ps[mi][j] = s; pd[mi][j] = d;
    }
  const int head = (col0 + wn) / CHEAD;
  if constexpr (DIRECT) {
    if ((lane & 15) == 0) {
      #pragma unroll
      for (int mi = 0; mi < FM; ++mi)
        #pragma unroll
        for (int j = 0; j < 4; ++j) {
          int rr = row0 + wm + mi * 16 + (lane >> 4) * 4 + j;
          if (rr < M) { es_g[rr * H + head] = ps[mi][j]; ed_g[rr * H + head] = pd[mi][j]; }
        }
    }
  } else {
    // head spans both wave col-groups (CHEAD == 2*FN*16): pair-add via LDS
    float* l_es = (float*)lds;
    float* l_ed = l_es + BM;
    __syncthreads();
    if ((wid & 1) == 0 && (lane & 15) == 0) {
      #pragma unroll
      for (int mi = 0; mi < FM; ++mi)
        #pragma unroll
        for (int j = 0; j < 4; ++j) {
          int rl = wm + mi * 16 + (lane >> 4) * 4 + j;
          l_es[rl] = ps[mi][j]; l_ed[rl] = pd[mi][j];
        }
    }
    __syncthreads();
    if ((wid & 1) == 1 && (lane & 15) == 0) {
      #pragma unroll
      for (int mi = 0; mi < FM; ++mi)
        #pragma unroll
        for (int j = 0; j < 4; ++j) {
          int rl = wm + mi * 16 + (lane >> 4) * 4 + j;
          int rr = row0 + rl;
          if (rr < M) {
            es_g[rr * H + head] = ps[mi][j] + l_es[rl];
            ed_g[rr * H + head] = pd[mi][j] + l_ed[rl];
          }
        }
    }
  }
}

// ---------------- wave-per-node GAT aggregation (G edge-parallel lane groups) ----------------
template<int VPT> struct GVec;
template<> struct GVec<16> { uint4 a, b; };
template<> struct GVec<8>  { uint4 a; };
template<> struct GVec<4>  { uint2 a; };

template<int VPT>
__device__ __forceinline__ GVec<VPT> gload(const __half* p) {
  GVec<VPT> v;
  if constexpr (VPT == 16) { v.a = *(const uint4*)p; v.b = *(const uint4*)(p + 8); }
  else if constexpr (VPT == 8) { v.a = *(const uint4*)p; }
  else { v.a = *(const uint2*)p; }
  return v;
}

template<int VPT>
__device__ __forceinline__ void gfma(const GVec<VPT>& u, float w, float* acc) {
  const __half2* p = (const __half2*)&u;
  #pragma unroll
  for (int j = 0; j < VPT / 2; ++j) {
    float2 f = __half22float2(p[j]);
    acc[2 * j]     += w * f.x;
    acc[2 * j + 1] += w * f.y;
  }
}

template<int H, int C, int G, bool RES_IN, bool F16_OUT, bool SCORER, int WPB>
__global__ __launch_bounds__(WPB * 64, 2) void gat_agg_wave(
    const __half* __restrict__ h, const float* __restrict__ es_g, const float* __restrict__ ed_g,
    const int* __restrict__ row_ptr, const int* __restrict__ csr_src,
    const float* __restrict__ bias, const float* __restrict__ gamma, const float* __restrict__ beta,
    const __half* __restrict__ res_in, int res_stride, __half* __restrict__ out_h,
    const float* __restrict__ sw1, const float* __restrict__ sb1,
    const float* __restrict__ sg1, const float* __restrict__ sbe1,
    const float* __restrict__ sw2, const float* __restrict__ sb2,
    const float* __restrict__ sg2, const float* __restrict__ sbe2,
    const float* __restrict__ sw3, const float* __restrict__ sb3,
    float* __restrict__ out)
{
  constexpr int HC   = H * C;
  constexpr int LPG  = 64 / G;        // lanes per group (one edge per group per step)
  constexpr int VPT  = HC / LPG;
  constexpr int CH   = 32;            // edges staged per chunk
  constexpr int BB   = 4;             // edges per load batch (G==1 path)
  constexpr int LOGH = (H == 8) ? 3 : ((H == 4) ? 2 : 1);
  constexpr int EPR  = 64 >> LOGH;    // (edge,head) pairs per round
  constexpr int ROUNDS = CH / EPR;
  constexpr int WST  = CH + 4;        // padded weight stride

  const int wave  = threadIdx.x >> 6;
  const int lane  = threadIdx.x & 63;
  const int grp   = lane / LPG;
  const int glane = lane % LPG;
  const int n     = blockIdx.x * WPB + wave;
  const int c0    = glane * VPT;
  const int myh   = c0 / C;
  const int wh    = lane & (H - 1);

  __shared__ int   s_lds[WPB][CH];
  __shared__ float w_lds[WPB][(H * WST < 64) ? 64 : H * WST];
  int*   sl = s_lds[wave];
  float* wl = w_lds[wave];

  const int p0 = row_ptr[n];
  const int p1 = row_ptr[n + 1];
  const float edw = ed_g[n * H + wh];

  float acc[VPT];
  #pragma unroll
  for (int j = 0; j < VPT; ++j) acc[j] = 0.f;
  float z = 0.f;

  for (int base = p0; base < p1; base += CH) {
    const int m = min(CH, p1 - base);
    // stage src indices (wave-synchronous LDS, no barrier)
    if (lane < CH) sl[lane] = (base + lane < p1) ? csr_src[base + lane] : n;
    // all (edge, head) weights, stored transposed [H][WST]; e >= m gets w = 0
    #pragma unroll
    for (int rr = 0; rr < ROUNDS; ++rr) {
      int e = (lane >> LOGH) + rr * EPR;
      int s = sl[e];
      float w = 0.f;
      if (base + e < p1) {
        float ev = es_g[s * H + wh] + edw;
        ev = (ev >= 0.f) ? ev : 0.2f * ev;
        w = __expf(ev);
      }
      wl[wh * WST + e] = w;
    }

    if constexpr (G == 1) {
      // whole-wave-per-edge, batched pipeline (proven L1 path)
      const int nb = m / BB;
      GVec<VPT> uA[BB], uB[BB];
      float4 wA, wB;
      auto LOADB = [&](int b, GVec<VPT> (&u)[BB], float4& w4) {
        int4 s4 = *(const int4*)&sl[b * BB];
        w4 = *(const float4*)&wl[myh * WST + b * BB];
        u[0] = gload<VPT>(h + (size_t)s4.x * HC + c0);
        u[1] = gload<VPT>(h + (size_t)s4.y * HC + c0);
        u[2] = gload<VPT>(h + (size_t)s4.z * HC + c0);
        u[3] = gload<VPT>(h + (size_t)s4.w * HC + c0);
      };
      auto FMAB = [&](GVec<VPT> (&u)[BB], float4& w4) {
        z += w4.x + w4.y + w4.z + w4.w;
        gfma<VPT>(u[0], w4.x, acc);
        gfma<VPT>(u[1], w4.y, acc);
        gfma<VPT>(u[2], w4.z, acc);
        gfma<VPT>(u[3], w4.w, acc);
      };
      if (nb > 0) LOADB(0, uA, wA);
      #pragma unroll
      for (int bb = 0; bb < CH / BB; bb += 2) {
        if (bb < nb) {
          if (bb + 1 < nb) LOADB(bb + 1, uB, wB);
          FMAB(uA, wA);
        }
        if (bb + 1 < nb) {
          if (bb + 2 < nb) LOADB(bb + 2, uA, wA);
          FMAB(uB, wB);
        }
      }
      for (int e = nb * BB; e < m; ++e) {
        int s = sl[e];
        float w = wl[myh * WST + e];
        z += w;
        GVec<VPT> u = gload<VPT>(h + (size_t)s * HC + c0);
        gfma<VPT>(u, w, acc);
      }
    } else {
      // G edge-parallel groups; group grp handles edges e = k*G + grp
      const int kG = (m + G - 1) / G;
      GVec<VPT> uA[2], uB[2];
      float wA[2], wB[2];
      auto LOADP = [&](int k, GVec<VPT> (&u)[2], float (&w)[2]) {
        #pragma unroll
        for (int t = 0; t < 2; ++t) {
          int kk = k + t;
          bool ok = kk < kG;
          int e = ok ? (kk * G + grp) : 0;
          int s = sl[e];
          w[t] = ok ? wl[myh * WST + e] : 0.f;
          u[t] = gload<VPT>(h + (size_t)s * HC + c0);
        }
      };
      auto FMAP = [&](GVec<VPT> (&u)[2], float (&w)[2]) {
        z += w[0] + w[1];
        gfma<VPT>(u[0], w[0], acc);
        gfma<VPT>(u[1], w[1], acc);
      };
      const int np = (kG + 1) >> 1;
      if (np > 0) LOADP(0, uA, wA);
      for (int p = 0; p < np; p += 2) {
        if (p + 1 < np) LOADP((p + 1) * 2, uB, wB);
        FMAP(uA, wA);
        if (p + 1 < np) {
          if (p + 2 < np) LOADP((p + 2) * 2, uA, wA);
          FMAP(uB, wB);
        }
      }
    }
  }

  // cross-group reduction (edge subsets are disjoint across groups)
  if constexpr (G > 1) {
    #pragma unroll
    for (int o = LPG; o < 64; o <<= 1) {
      #pragma unroll
      for (int j = 0; j < VPT; ++j) acc[j] += __shfl_xor(acc[j], o);
      z += __shfl_xor(z, o);
    }
  }

  // normalize + bias + relu
  float inv = 1.f / (z + 1e-16f);
  float ov[VPT];
  float psum = 0.f, psq = 0.f;
  #pragma unroll
  for (int j = 0; j < VPT; ++j) {
    float x = fmaxf(acc[j] * inv + bias[c0 + j], 0.f);
    ov[j] = x; psum += x; psq += x * x;
  }
  #pragma unroll
  for (int o = 32; o > 0; o >>= 1) {
    psum += __shfl_xor(psum, o);
    psq  += __shfl_xor(psq, o);
  }
  float mu  = psum / (float)(HC * G);
  float var = psq / (float)(HC * G) - mu * mu;
  float rs  = rsqrtf(var + 1e-5f);

  ushortT hb[VPT];
  #pragma unroll
  for (int j = 0; j < VPT; ++j) {
    int c = c0 + j;
    float o = (ov[j] - mu) * rs * gamma[c] + beta[c];
    if constexpr (RES_IN) {
      if (grp == 0) o += __half2float(res_in[(size_t)n * res_stride + c]);
    }
    ov[j] = o;
    if constexpr (F16_OUT) hb[j] = __half_as_ushort(__float2half(o));
  }
  if constexpr (F16_OUT) {
    if (grp == 0) {
      ushortT* po = (ushortT*)out_h + (size_t)n * HC + c0;
      if constexpr (VPT == 16) {
        *(uint4*)po       = *(uint4*)&hb[0];
        *(uint4*)(po + 8) = *(uint4*)&hb[8];
      } else if constexpr (VPT == 8) {
        *(uint4*)po = *(uint4*)&hb[0];
      } else {
        *(uint2*)po = *(uint2*)&hb[0];
      }
    }
  }

  if constexpr (SCORER) {
    // group 0 holds the 64-dim h3 row; spread to per-lane channels via LDS (wave-local)
    if (grp == 0) {
      #pragma unroll
      for (int j = 0; j < VPT; ++j) wl[c0 + j] = ov[j];
    }
    float s1 = sb1[lane];
    #pragma unroll 16
    for (int k = 0; k < 64; ++k) s1 += wl[k] * sw1[k * 64 + lane];
    s1 = fmaxf(s1, 0.f);
    float su = s1, sq = s1 * s1;
    #pragma unroll
    for (int o = 32; o > 0; o >>= 1) { su += __shfl_xor(su, o); sq += __shfl_xor(sq, o); }
    float mu1 = su * (1.f / 64.f), var1 = sq * (1.f / 64.f) - mu1 * mu1;
    float v1 = (s1 - mu1) * rsqrtf(var1 + 1e-5f) * sg1[lane] + sbe1[lane];
    wl[lane] = v1;
    float o2 = 0.f;
    if (lane < 32) {
      o2 = sb2[lane];
      #pragma unroll 16
      for (int k = 0; k < 64; ++k) o2 += wl[k] * sw2[k * 32 + lane];
      o2 = fmaxf(o2, 0.f);
    }
    float su2 = o2, sq2 = o2 * o2;
    #pragma unroll
    for (int o = 16; o > 0; o >>= 1) { su2 += __shfl_xor(su2, o); sq2 += __shfl_xor(sq2, o); }
    float p = 0.f;
    if (lane < 32) {
      float mu2 = su2 * (1.f / 32.f), var2 = sq2 * (1.f / 32.f) - mu2 * mu2;
      float v2 = (o2 - mu2) * rsqrtf(var2 + 1e-5f) * sg2[lane] + sbe2[lane];
      p = v2 * sw3[lane];
    }
    #pragma unroll
    for (int o = 16; o > 0; o >>= 1) p += __shfl_xor(p, o);
    if (lane == 0) out[n] = 1.f / (1.f + expf(-(p + sb3[0])));
  }
}

// ---------------- launch ----------------
extern "C" void kernel_launch(void* const* d_in, const int* in_sizes, int n_in,
                              void* d_out, int out_size, void* d_ws, size_t ws_size,
                              hipStream_t stream)
{
  const float* x    = (const float*)d_in[0];
  const int*   ei   = (const int*)d_in[1];
  const float* w1   = (const float*)d_in[2];
  const float* as1  = (const float*)d_in[3];
  const float* ad1  = (const float*)d_in[4];
  const float* b1   = (const float*)d_in[5];
  const float* g1v  = (const float*)d_in[6];
  const float* be1  = (const float*)d_in[7];
  const float* w2   = (const float*)d_in[8];
  const float* as2  = (const float*)d_in[9];
  const float* ad2  = (const float*)d_in[10];
  const float* b2   = (const float*)d_in[11];
  const float* g2v  = (const float*)d_in[12];
  const float* be2  = (const float*)d_in[13];
  const float* w3   = (const float*)d_in[14];
  const float* as3  = (const float*)d_in[15];
  const float* ad3  = (const float*)d_in[16];
  const float* b3   = (const float*)d_in[17];
  const float* g3v  = (const float*)d_in[18];
  const float* be3  = (const float*)d_in[19];
  const float* sw1  = (const float*)d_in[20];
  const float* sb1  = (const float*)d_in[21];
  const float* sg1  = (const float*)d_in[22];
  const float* sbe1 = (const float*)d_in[23];
  const float* sw2  = (const float*)d_in[24];
  const float* sb2  = (const float*)d_in[25];
  const float* sg2  = (const float*)d_in[26];
  const float* sbe2 = (const float*)d_in[27];
  const float* sw3  = (const float*)d_in[28];
  const float* sb3  = (const float*)d_in[29];
  float* out = (float*)d_out;

  char* ws = (char*)d_ws;
  size_t off = 0;
  auto alloc = [&](size_t bytes) -> void* {
    off = (off + 255) & ~(size_t)255;
    void* p = ws + off;
    off += bytes;
    return p;
  };

  __half*  h_gemm  = (__half*)alloc((size_t)NN * 1024 * 2);  // GEMM outputs (all layers)
  __half*  h1_f16  = (__half*)alloc((size_t)NN * 1024 * 2);  // L1 post-LN (gemm2 A + L2 residual)
  __half*  h2_f16  = (__half*)alloc((size_t)NN * 256 * 2);   // L2 post-LN (gemm3 A + L3 residual)
  __half*  x16     = (__half*)alloc((size_t)NN * 512 * 2);   // x fp16 (gemm1 A)
  ushortT* w1t     = (ushortT*)alloc((size_t)512 * 1024 * 2);
  ushortT* w2t     = (ushortT*)alloc((size_t)1024 * 256 * 2);
  ushortT* w3t     = (ushortT*)alloc((size_t)256 * 64 * 2);
  float*   es_buf  = (float*)alloc((size_t)NN * 8 * 4);
  float*   ed_buf  = (float*)alloc((size_t)NN * 8 * 4);
  int*     deg     = (int*)alloc((size_t)NN * 4);
  int*     row_ptr = (int*)alloc((size_t)(NN + 1) * 4);
  int*     cursor  = (int*)alloc((size_t)NN * 4);
  int*     csr_src = (int*)alloc((size_t)ETOT * 4);
  (void)ws_size; (void)in_sizes; (void)n_in; (void)out_size;

  // fused preprocessing (x cast + w transposes + degree hist), then CSR
  hipMemsetAsync(deg, 0, (size_t)NN * 4, stream);
  preproc_kernel<<<2048, 256, 0, stream>>>(x, x16, w1, w1t, w2, w2t, w3, w3t, ei, deg);
  scan_kernel<<<1, 1024, 0, stream>>>(deg, row_ptr, cursor);
  scatter_kernel<<<(ETOT + 255) / 256, 256, 0, stream>>>(ei, cursor, csr_src);

  const int MB = (NN + 127) / 128;  // 157

  // ---- layer 1: 512 -> 8 x 128 ----
  gemm_f16<128, 128, 4, 4, 128><<<dim3(MB, 1024 / 128), 256, 0, stream>>>(
      x16, w1t, h_gemm, NN, 1024, 512, as1, ad1, es_buf, ed_buf, 8);
  gat_agg_wave<8, 128, 1, false, true, false, 4><<<NN / 4, 256, 0, stream>>>(
      h_gemm, es_buf, ed_buf, row_ptr, csr_src, b1, g1v, be1,
      nullptr, 0, h1_f16,
      nullptr, nullptr, nullptr, nullptr, nullptr, nullptr, nullptr, nullptr, nullptr, nullptr, nullptr);

  // ---- layer 2: 1024 -> 4 x 64 ----
  gemm_f16<128, 128, 4, 4, 64><<<dim3(MB, 256 / 128), 256, 0, stream>>>(
      h1_f16, w2t, h_gemm, NN, 256, 1024, as2, ad2, es_buf, ed_buf, 4);
  gat_agg_wave<4, 64, 2, true, true, false, 4><<<NN / 4, 256, 0, stream>>>(
      h_gemm, es_buf, ed_buf, row_ptr, csr_src, b2, g2v, be2,
      h1_f16, 1024, h2_f16,
      nullptr, nullptr, nullptr, nullptr, nullptr, nullptr, nullptr, nullptr, nullptr, nullptr, nullptr);

  // ---- layer 3: 256 -> 2 x 32 (+ fused scorer MLP) ----
  gemm_f16<128, 64, 4, 2, 32><<<dim3(MB, 1), 256, 0, stream>>>(
      h2_f16, w3t, h_gemm, NN, 64, 256, as3, ad3, es_buf, ed_buf, 2);
  gat_agg_wave<2, 32, 8, true, false, true, 4><<<NN / 4, 256, 0, stream>>>(
      h_gemm, es_buf, ed_buf, row_ptr, csr_src, b3, g3v, be3,
      h2_f16, 256, nullptr,
      sw1, sb1, sg1, sbe1, sw2, sb2, sg2, sbe2, sw3, sb3, out);
}

// Round 11
// 317.085 us; speedup vs baseline: 1.0333x; 1.0333x over previous
//
#include <hip/hip_runtime.h>
#include <hip/hip_bf16.h>
#include <hip/hip_fp16.h>
#include <cstdint>

#define NN 20000
#define EE 320000
#define ETOT (EE + NN)

using f32x4 = __attribute__((ext_vector_type(4))) float;
using f16x8 = __attribute__((ext_vector_type(8))) _Float16;
typedef unsigned short ushortT;

// ---------------- fused preprocessing: x-cast + weight transposes + degree hist ----------------
__global__ __launch_bounds__(256) void preproc_kernel(
    const float* __restrict__ x, __half* __restrict__ x16,
    const float* __restrict__ w1, ushortT* __restrict__ w1t,
    const float* __restrict__ w2, ushortT* __restrict__ w2t,
    const float* __restrict__ w3, ushortT* __restrict__ w3t,
    const int* __restrict__ ei, int* __restrict__ deg)
{
  constexpr int N0 = NN * 512;        // x cast
  constexpr int N1 = 512 * 1024;      // w1 transpose
  constexpr int N2 = 1024 * 256;      // w2 transpose
  constexpr int N3 = 256 * 64;        // w3 transpose
  constexpr int TOT = N0 + N1 + N2 + N3 + ETOT;
  for (int i = blockIdx.x * 256 + threadIdx.x; i < TOT; i += gridDim.x * 256) {
    int j = i;
    if (j < N0) { x16[j] = __float2half(x[j]); continue; }
    j -= N0;
    if (j < N1) {
      int k = j >> 10, c = j & 1023;
      w1t[(size_t)c * 512 + k] = __half_as_ushort(__float2half(w1[j]));
      continue;
    }
    j -= N1;
    if (j < N2) {
      int k = j >> 8, c = j & 255;
      w2t[(size_t)c * 1024 + k] = __half_as_ushort(__float2half(w2[j]));
      continue;
    }
    j -= N2;
    if (j < N3) {
      int k = j >> 6, c = j & 63;
      w3t[(size_t)c * 256 + k] = __half_as_ushort(__float2half(w3[j]));
      continue;
    }
    j -= N3;
    int d = (j < EE) ? ei[EE + j] : (j - EE);
    atomicAdd(&deg[d], 1);
  }
}

__global__ __launch_bounds__(1024) void scan_kernel(const int* __restrict__ deg,
                                                    int* __restrict__ row_ptr,
                                                    int* __restrict__ cursor) {
  __shared__ int partial[1024];
  const int t = threadIdx.x;
  constexpr int PER = (NN + 1023) / 1024;  // 20
  const int base = t * PER;
  int vals[PER];
  int local = 0;
  #pragma unroll
  for (int j = 0; j < PER; ++j) {
    int i = base + j;
    int v = (i < NN) ? deg[i] : 0;
    vals[j] = v; local += v;
  }
  partial[t] = local;
  __syncthreads();
  for (int off = 1; off < 1024; off <<= 1) {
    int x = (t >= off) ? partial[t - off] : 0;
    __syncthreads();
    partial[t] += x;
    __syncthreads();
  }
  int prefix = partial[t] - local;  // exclusive
  #pragma unroll
  for (int j = 0; j < PER; ++j) {
    int i = base + j;
    if (i < NN) { row_ptr[i] = prefix; cursor[i] = prefix; }
    prefix += vals[j];
  }
  if (t == 1023) row_ptr[NN] = prefix;
}

__global__ void scatter_kernel(const int* __restrict__ ei, int* __restrict__ cursor,
                               int* __restrict__ csr_src) {
  int i = blockIdx.x * 256 + threadIdx.x;
  if (i >= ETOT) return;
  int s, d;
  if (i < EE) { s = ei[i]; d = ei[EE + i]; } else { s = d = i - EE; }
  int pos = atomicAdd(&cursor[d], 1);
  csr_src[pos] = s;
}

// ---------------- fp16 MFMA GEMM (double-buffered, counted vmcnt) ----------------
__device__ __forceinline__ void gload16(const void* g, void* l) {
  __builtin_amdgcn_global_load_lds((const __attribute__((address_space(1))) void*)g,
                                   (__attribute__((address_space(3))) void*)l, 16, 0, 0);
}

template<int N> __device__ __forceinline__ void wait_vm() {
  if constexpr (N == 0) asm volatile("s_waitcnt vmcnt(0)" ::: "memory");
  else if constexpr (N == 2) asm volatile("s_waitcnt vmcnt(2)" ::: "memory");
  else if constexpr (N == 3) asm volatile("s_waitcnt vmcnt(3)" ::: "memory");
  else if constexpr (N == 4) asm volatile("s_waitcnt vmcnt(4)" ::: "memory");
  else if constexpr (N == 6) asm volatile("s_waitcnt vmcnt(6)" ::: "memory");
  else if constexpr (N == 8) asm volatile("s_waitcnt vmcnt(8)" ::: "memory");
  else static_assert(N <= 8, "unsupported vmcnt");
}

// C[M][Ncols] = A[M][K] * Bt[Ncols][K]^T; also es/ed = rowwise dot(h, asrc/adst) per head.
template<int BM, int BN, int FM, int FN, int CHEAD>
__global__ __launch_bounds__(256) void gemm_f16(
    const __half* __restrict__ A,
    const ushortT* __restrict__ Bt,
    __half* __restrict__ C, int M, int Ncols, int K,
    const float* __restrict__ asrc, const float* __restrict__ adst,
    float* __restrict__ es_g, float* __restrict__ ed_g, int H)
{
  constexpr int BK   = 32;
  constexpr int HALF = (BM + BN) * BK;              // elems per buffer
  constexpr int NL   = (BM * 4 + BN * 4) / 256;     // stage loads per thread
  __shared__ ushortT lds[2 * HALF];

  const int tid  = threadIdx.x;
  const int lane = tid & 63;
  const int wid  = tid >> 6;
  const int wm   = (wid >> 1) * (FM * 16);
  const int wn   = (wid & 1) * (FN * 16);
  const int row0 = blockIdx.x * BM;
  const int col0 = blockIdx.y * BN;
  const int r    = lane & 15;
  const int kg   = lane >> 4;

  const ushortT* Au = (const ushortT*)A;

  auto STAGE = [&](int buf, int k0) {
    ushortT* sA = lds + buf * HALF;
    ushortT* sB = sA + BM * BK;
    #pragma unroll
    for (int i = tid; i < BM * 4; i += 256) {
      int row = i >> 2, slot = i & 3;
      int gs = slot ^ (row & 3);
      int grow = row0 + row; if (grow > M - 1) grow = M - 1;
      gload16(Au + (size_t)grow * K + k0 + gs * 8, sA + row * BK + slot * 8);
    }
    #pragma unroll
    for (int i = tid; i < BN * 4; i += 256) {
      int row = i >> 2, slot = i & 3;
      int gs = slot ^ (row & 3);
      gload16(Bt + (size_t)(col0 + row) * K + k0 + gs * 8, sB + row * BK + slot * 8);
    }
  };

  f32x4 acc[FM][FN] = {};
  const int nt = K / BK;

  STAGE(0, 0);
  for (int t = 0; t < nt; ++t) {
    if (t + 1 < nt) { STAGE((t + 1) & 1, (t + 1) * BK); wait_vm<NL>(); }
    else            { wait_vm<0>(); }
    __builtin_amdgcn_s_barrier();
    __builtin_amdgcn_sched_barrier(0);

    const ushortT* sA = lds + (t & 1) * HALF;
    const ushortT* sB = sA + BM * BK;
    const int ks = (kg ^ (r & 3)) * 8;
    f16x8 a[FM], b[FN];
    #pragma unroll
    for (int mi = 0; mi < FM; ++mi)
      a[mi] = *(const f16x8*)(sA + (wm + mi * 16 + r) * BK + ks);
    #pragma unroll
    for (int ni = 0; ni < FN; ++ni)
      b[ni] = *(const f16x8*)(sB + (wn + ni * 16 + r) * BK + ks);
    #pragma unroll
    for (int mi = 0; mi < FM; ++mi)
      #pragma unroll
      for (int ni = 0; ni < FN; ++ni)
        acc[mi][ni] = __builtin_amdgcn_mfma_f32_16x16x32_f16(a[mi], b[ni], acc[mi][ni], 0, 0, 0);
    __builtin_amdgcn_sched_barrier(0);
    __builtin_amdgcn_s_barrier();
  }

  // C-write
  #pragma unroll
  for (int mi = 0; mi < FM; ++mi) {
    int rb = row0 + wm + mi * 16 + (lane >> 4) * 4;
    #pragma unroll
    for (int ni = 0; ni < FN; ++ni) {
      int cc = col0 + wn + ni * 16 + (lane & 15);
      #pragma unroll
      for (int j = 0; j < 4; ++j) {
        int rr = rb + j;
        if (rr < M) C[(size_t)rr * Ncols + cc] = __float2half(acc[mi][ni][j]);
      }
    }
  }

  // fused es/ed epilogue. Wave col-group covers FN*16 cols; head spans CHEAD cols.
  constexpr bool DIRECT = (CHEAD == FN * 16);
  float av[FN], dv[FN];
  #pragma unroll
  for (int ni = 0; ni < FN; ++ni) {
    int cc = col0 + wn + ni * 16 + (lane & 15);
    av[ni] = asrc[cc];
    dv[ni] = adst[cc];
  }
  float ps[FM][4], pd[FM][4];
  #pragma unroll
  for (int mi = 0; mi < FM; ++mi)
    #pragma unroll
    for (int j = 0; j < 4; ++j) {
      float s = 0.f, d = 0.f;
      #pragma unroll
      for (int ni = 0; ni < FN; ++ni) {
        float v = acc[mi][ni][j];
        s += v * av[ni];
        d += v * dv[ni];
      }
      #pragma unroll
      for (int off = 8; off; off >>= 1) {
        s += __shfl_xor(s, off);
        d += __shfl_xor(d, off);
      }
      ps[mi][j] = s; pd[mi][j] = d;
    }
  const int head = (col0 + wn) / CHEAD;
  if constexpr (DIRECT) {
    if ((lane & 15) == 0) {
      #pragma unroll
      for (int mi = 0; mi < FM; ++mi)
        #pragma unroll
        for (int j = 0; j < 4; ++j) {
          int rr = row0 + wm + mi * 16 + (lane >> 4) * 4 + j;
          if (rr < M) { es_g[rr * H + head] = ps[mi][j]; ed_g[rr * H + head] = pd[mi][j]; }
        }
    }
  } else {
    // head spans both wave col-groups (CHEAD == 2*FN*16): pair-add via LDS
    float* l_es = (float*)lds;
    float* l_ed = l_es + BM;
    __syncthreads();
    if ((wid & 1) == 0 && (lane & 15) == 0) {
      #pragma unroll
      for (int mi = 0; mi < FM; ++mi)
        #pragma unroll
        for (int j = 0; j < 4; ++j) {
          int rl = wm + mi * 16 + (lane >> 4) * 4 + j;
          l_es[rl] = ps[mi][j]; l_ed[rl] = pd[mi][j];
        }
    }
    __syncthreads();
    if ((wid & 1) == 1 && (lane & 15) == 0) {
      #pragma unroll
      for (int mi = 0; mi < FM; ++mi)
        #pragma unroll
        for (int j = 0; j < 4; ++j) {
          int rl = wm + mi * 16 + (lane >> 4) * 4 + j;
          int rr = row0 + rl;
          if (rr < M) {
            es_g[rr * H + head] = ps[mi][j] + l_es[rl];
            ed_g[rr * H + head] = pd[mi][j] + l_ed[rl];
          }
        }
    }
  }
}

// ---------------- wave-per-node GAT aggregation (batched-DS, pipelined) ----------------
template<int VPT> struct GVec;
template<> struct GVec<16> { uint4 a, b; };
template<> struct GVec<4>  { uint2 a; };
template<> struct GVec<1>  { ushortT a; };

template<int VPT>
__device__ __forceinline__ GVec<VPT> gload(const __half* p) {
  GVec<VPT> v;
  if constexpr (VPT == 16) { v.a = *(const uint4*)p; v.b = *(const uint4*)(p + 8); }
  else if constexpr (VPT == 4) { v.a = *(const uint2*)p; }
  else { v.a = *(const ushortT*)p; }
  return v;
}

template<int VPT>
__device__ __forceinline__ void gfma(const GVec<VPT>& u, float w, float* acc) {
  if constexpr (VPT == 1) {
    __half hv;
    *(ushortT*)&hv = u.a;
    acc[0] += w * __half2float(hv);
  } else {
    const __half2* p = (const __half2*)&u;
    #pragma unroll
    for (int j = 0; j < VPT / 2; ++j) {
      float2 f = __half22float2(p[j]);
      acc[2 * j]     += w * f.x;
      acc[2 * j + 1] += w * f.y;
    }
  }
}

template<int H, int C, bool RES_IN, bool F16_OUT, bool SCORER, int WPB>
__global__ __launch_bounds__(WPB * 64, 2) void gat_agg_wave(
    const __half* __restrict__ h, const float* __restrict__ es_g, const float* __restrict__ ed_g,
    const int* __restrict__ row_ptr, const int* __restrict__ csr_src,
    const float* __restrict__ bias, const float* __restrict__ gamma, const float* __restrict__ beta,
    const __half* __restrict__ res_in, int res_stride, __half* __restrict__ out_h,
    const float* __restrict__ sw1, const float* __restrict__ sb1,
    const float* __restrict__ sg1, const float* __restrict__ sbe1,
    const float* __restrict__ sw2, const float* __restrict__ sb2,
    const float* __restrict__ sg2, const float* __restrict__ sbe2,
    const float* __restrict__ sw3, const float* __restrict__ sb3,
    float* __restrict__ out)
{
  constexpr int HC   = H * C;
  constexpr int VPT  = HC / 64;
  constexpr int CH   = 32;            // edges staged per chunk
  constexpr int BB   = 4;             // edges per load batch
  constexpr int LOGH = (H == 8) ? 3 : ((H == 4) ? 2 : 1);
  constexpr int EPR  = 64 >> LOGH;    // (edge,head) pairs per round
  constexpr int ROUNDS = CH / EPR;
  constexpr int WST  = CH + 4;        // padded weight stride (bank-spread)

  const int wave = threadIdx.x >> 6;
  const int lane = threadIdx.x & 63;
  const int n    = blockIdx.x * WPB + wave;
  const int c0   = lane * VPT;
  const int myh  = c0 / C;
  const int wh   = lane & (H - 1);

  __shared__ int   s_lds[WPB][CH];
  __shared__ float w_lds[WPB][(H * WST < 64) ? 64 : H * WST];
  int*   sl = s_lds[wave];
  float* wl = w_lds[wave];

  const int p0 = row_ptr[n];
  const int p1 = row_ptr[n + 1];
  const float edw = ed_g[n * H + wh];

  float acc[VPT];
  #pragma unroll
  for (int j = 0; j < VPT; ++j) acc[j] = 0.f;
  float z = 0.f;

  for (int base = p0; base < p1; base += CH) {
    const int m = min(CH, p1 - base);
    // stage src indices (wave-synchronous LDS, no barrier)
    if (lane < CH) sl[lane] = (base + lane < p1) ? csr_src[base + lane] : n;
    // all (edge, head) weights, stored transposed [H][WST]
    #pragma unroll
    for (int rr = 0; rr < ROUNDS; ++rr) {
      int e = (lane >> LOGH) + rr * EPR;
      int s = sl[e];
      float w = 0.f;
      if (base + e < p1) {
        float ev = es_g[s * H + wh] + edw;
        ev = (ev >= 0.f) ? ev : 0.2f * ev;
        w = __expf(ev);
      }
      wl[wh * WST + e] = w;
    }

    // pipelined gather
    const int nb = m / BB;
    GVec<VPT> uA[BB], uB[BB];
    float4 wA, wB;

    auto LOADB = [&](int b, GVec<VPT> (&u)[BB], float4& w4) {
      int4 s4 = *(const int4*)&sl[b * BB];
      w4 = *(const float4*)&wl[myh * WST + b * BB];
      u[0] = gload<VPT>(h + (size_t)s4.x * HC + c0);
      u[1] = gload<VPT>(h + (size_t)s4.y * HC + c0);
      u[2] = gload<VPT>(h + (size_t)s4.z * HC + c0);
      u[3] = gload<VPT>(h + (size_t)s4.w * HC + c0);
    };
    auto FMAB = [&](GVec<VPT> (&u)[BB], float4& w4) {
      z += w4.x + w4.y + w4.z + w4.w;
      gfma<VPT>(u[0], w4.x, acc);
      gfma<VPT>(u[1], w4.y, acc);
      gfma<VPT>(u[2], w4.z, acc);
      gfma<VPT>(u[3], w4.w, acc);
    };

    if (nb > 0) LOADB(0, uA, wA);
    #pragma unroll
    for (int bb = 0; bb < CH / BB; bb += 2) {
      if (bb < nb) {
        if (bb + 1 < nb) LOADB(bb + 1, uB, wB);
        FMAB(uA, wA);
      }
      if (bb + 1 < nb) {
        if (bb + 2 < nb) LOADB(bb + 2, uA, wA);
        FMAB(uB, wB);
      }
    }
    // tail
    for (int e = nb * BB; e < m; ++e) {
      int s = sl[e];
      float w = wl[myh * WST + e];
      z += w;
      GVec<VPT> u = gload<VPT>(h + (size_t)s * HC + c0);
      gfma<VPT>(u, w, acc);
    }
  }

  // normalize + bias + relu
  float inv = 1.f / (z + 1e-16f);
  float ov[VPT];
  float psum = 0.f, psq = 0.f;
  #pragma unroll
  for (int j = 0; j < VPT; ++j) {
    float x = fmaxf(acc[j] * inv + bias[c0 + j], 0.f);
    ov[j] = x; psum += x; psq += x * x;
  }
  #pragma unroll
  for (int o = 32; o > 0; o >>= 1) {
    psum += __shfl_xor(psum, o);
    psq  += __shfl_xor(psq, o);
  }
  float mu  = psum / (float)HC;
  float var = psq / (float)HC - mu * mu;
  float rs  = rsqrtf(var + 1e-5f);

  ushortT hb[VPT > 1 ? VPT : 2];
  #pragma unroll
  for (int j = 0; j < VPT; ++j) {
    int c = c0 + j;
    float o = (ov[j] - mu) * rs * gamma[c] + beta[c];
    if constexpr (RES_IN) o += __half2float(res_in[(size_t)n * res_stride + c]);
    ov[j] = o;
    if constexpr (F16_OUT) hb[j] = __half_as_ushort(__float2half(o));
  }
  if constexpr (F16_OUT) {
    ushortT* po = (ushortT*)out_h + (size_t)n * HC + c0;
    if constexpr (VPT == 16) {
      *(uint4*)po       = *(uint4*)&hb[0];
      *(uint4*)(po + 8) = *(uint4*)&hb[8];
    } else if constexpr (VPT == 4) {
      *(uint2*)po = *(uint2*)&hb[0];
    } else {
      *po = hb[0];
    }
  }

  if constexpr (SCORER) {
    // VPT==1: lane holds h3 channel `lane` in ov[0]. Wave-local MLP (no barriers).
    wl[lane] = ov[0];
    float s1 = sb1[lane];
    #pragma unroll 16
    for (int k = 0; k < 64; ++k) s1 += wl[k] * sw1[k * 64 + lane];
    s1 = fmaxf(s1, 0.f);
    float su = s1, sq = s1 * s1;
    #pragma unroll
    for (int o = 32; o > 0; o >>= 1) { su += __shfl_xor(su, o); sq += __shfl_xor(sq, o); }
    float mu1 = su * (1.f / 64.f), var1 = sq * (1.f / 64.f) - mu1 * mu1;
    float v1 = (s1 - mu1) * rsqrtf(var1 + 1e-5f) * sg1[lane] + sbe1[lane];
    wl[lane] = v1;
    float o2 = 0.f;
    if (lane < 32) {
      o2 = sb2[lane];
      #pragma unroll 16
      for (int k = 0; k < 64; ++k) o2 += wl[k] * sw2[k * 32 + lane];
      o2 = fmaxf(o2, 0.f);
    }
    float su2 = o2, sq2 = o2 * o2;
    #pragma unroll
    for (int o = 16; o > 0; o >>= 1) { su2 += __shfl_xor(su2, o); sq2 += __shfl_xor(sq2, o); }
    float p = 0.f;
    if (lane < 32) {
      float mu2 = su2 * (1.f / 32.f), var2 = sq2 * (1.f / 32.f) - mu2 * mu2;
      float v2 = (o2 - mu2) * rsqrtf(var2 + 1e-5f) * sg2[lane] + sbe2[lane];
      p = v2 * sw3[lane];
    }
    #pragma unroll
    for (int o = 16; o > 0; o >>= 1) p += __shfl_xor(p, o);
    if (lane == 0) out[n] = 1.f / (1.f + expf(-(p + sb3[0])));
  }
}

// ---------------- launch ----------------
extern "C" void kernel_launch(void* const* d_in, const int* in_sizes, int n_in,
                              void* d_out, int out_size, void* d_ws, size_t ws_size,
                              hipStream_t stream)
{
  const float* x    = (const float*)d_in[0];
  const int*   ei   = (const int*)d_in[1];
  const float* w1   = (const float*)d_in[2];
  const float* as1  = (const float*)d_in[3];
  const float* ad1  = (const float*)d_in[4];
  const float* b1   = (const float*)d_in[5];
  const float* g1v  = (const float*)d_in[6];
  const float* be1  = (const float*)d_in[7];
  const float* w2   = (const float*)d_in[8];
  const float* as2  = (const float*)d_in[9];
  const float* ad2  = (const float*)d_in[10];
  const float* b2   = (const float*)d_in[11];
  const float* g2v  = (const float*)d_in[12];
  const float* be2  = (const float*)d_in[13];
  const float* w3   = (const float*)d_in[14];
  const float* as3  = (const float*)d_in[15];
  const float* ad3  = (const float*)d_in[16];
  const float* b3   = (const float*)d_in[17];
  const float* g3v  = (const float*)d_in[18];
  const float* be3  = (const float*)d_in[19];
  const float* sw1  = (const float*)d_in[20];
  const float* sb1  = (const float*)d_in[21];
  const float* sg1  = (const float*)d_in[22];
  const float* sbe1 = (const float*)d_in[23];
  const float* sw2  = (const float*)d_in[24];
  const float* sb2  = (const float*)d_in[25];
  const float* sg2  = (const float*)d_in[26];
  const float* sbe2 = (const float*)d_in[27];
  const float* sw3  = (const float*)d_in[28];
  const float* sb3  = (const float*)d_in[29];
  float* out = (float*)d_out;

  char* ws = (char*)d_ws;
  size_t off = 0;
  auto alloc = [&](size_t bytes) -> void* {
    off = (off + 255) & ~(size_t)255;
    void* p = ws + off;
    off += bytes;
    return p;
  };

  __half*  h_gemm  = (__half*)alloc((size_t)NN * 1024 * 2);  // GEMM outputs (all layers)
  __half*  h1_f16  = (__half*)alloc((size_t)NN * 1024 * 2);  // L1 post-LN (gemm2 A + L2 residual)
  __half*  h2_f16  = (__half*)alloc((size_t)NN * 256 * 2);   // L2 post-LN (gemm3 A + L3 residual)
  __half*  x16     = (__half*)alloc((size_t)NN * 512 * 2);   // x fp16 (gemm1 A)
  ushortT* w1t     = (ushortT*)alloc((size_t)512 * 1024 * 2);
  ushortT* w2t     = (ushortT*)alloc((size_t)1024 * 256 * 2);
  ushortT* w3t     = (ushortT*)alloc((size_t)256 * 64 * 2);
  float*   es_buf  = (float*)alloc((size_t)NN * 8 * 4);
  float*   ed_buf  = (float*)alloc((size_t)NN * 8 * 4);
  int*     deg     = (int*)alloc((size_t)NN * 4);
  int*     row_ptr = (int*)alloc((size_t)(NN + 1) * 4);
  int*     cursor  = (int*)alloc((size_t)NN * 4);
  int*     csr_src = (int*)alloc((size_t)ETOT * 4);
  (void)ws_size; (void)in_sizes; (void)n_in; (void)out_size;

  // fused preprocessing (x cast + w transposes + degree hist), then CSR
  hipMemsetAsync(deg, 0, (size_t)NN * 4, stream);
  preproc_kernel<<<2048, 256, 0, stream>>>(x, x16, w1, w1t, w2, w2t, w3, w3t, ei, deg);
  scan_kernel<<<1, 1024, 0, stream>>>(deg, row_ptr, cursor);
  scatter_kernel<<<(ETOT + 255) / 256, 256, 0, stream>>>(ei, cursor, csr_src);

  const int MB = (NN + 127) / 128;  // 157

  // ---- layer 1: 512 -> 8 x 128 ----
  gemm_f16<128, 128, 4, 4, 128><<<dim3(MB, 1024 / 128), 256, 0, stream>>>(
      x16, w1t, h_gemm, NN, 1024, 512, as1, ad1, es_buf, ed_buf, 8);
  gat_agg_wave<8, 128, false, true, false, 4><<<NN / 4, 256, 0, stream>>>(
      h_gemm, es_buf, ed_buf, row_ptr, csr_src, b1, g1v, be1,
      nullptr, 0, h1_f16,
      nullptr, nullptr, nullptr, nullptr, nullptr, nullptr, nullptr, nullptr, nullptr, nullptr, nullptr);

  // ---- layer 2: 1024 -> 4 x 64 ----
  gemm_f16<128, 128, 4, 4, 64><<<dim3(MB, 256 / 128), 256, 0, stream>>>(
      h1_f16, w2t, h_gemm, NN, 256, 1024, as2, ad2, es_buf, ed_buf, 4);
  gat_agg_wave<4, 64, true, true, false, 4><<<NN / 4, 256, 0, stream>>>(
      h_gemm, es_buf, ed_buf, row_ptr, csr_src, b2, g2v, be2,
      h1_f16, 1024, h2_f16,
      nullptr, nullptr, nullptr, nullptr, nullptr, nullptr, nullptr, nullptr, nullptr, nullptr, nullptr);

  // ---- layer 3: 256 -> 2 x 32 (+ fused scorer MLP) ----
  gemm_f16<128, 64, 4, 2, 32><<<dim3(MB, 1), 256, 0, stream>>>(
      h2_f16, w3t, h_gemm, NN, 64, 256, as3, ad3, es_buf, ed_buf, 2);
  gat_agg_wave<2, 32, true, false, true, 4><<<NN / 4, 256, 0, stream>>>(
      h_gemm, es_buf, ed_buf, row_ptr, csr_src, b3, g3v, be3,
      h2_f16, 256, nullptr,
      sw1, sb1, sg1, sbe1, sw2, sb2, sg2, sbe2, sw3, sb3, out);
}